// Round 7
// baseline (136.765 us; speedup 1.0000x reference)
//
#include <hip/hip_runtime.h>
#include <hip/hip_bf16.h>
#include <math.h>

namespace {

constexpr int B_ = 8, L_ = 4096, C_ = 128, K_ = 7;
constexpr int LP = L_ - K_ + 1;        // 4090
constexpr int CK = C_ * K_;            // 896

typedef __attribute__((ext_vector_type(8))) short short8v;
typedef __attribute__((ext_vector_type(4))) float f32x4;

__device__ __forceinline__ unsigned short bf16_rne(float f) {
    __hip_bfloat16 h = __float2bfloat16(f);
    return *reinterpret_cast<unsigned short*>(&h);
}

__device__ __forceinline__ float fast_tanh(float v) {
    float a = fabsf(v);
    float e = __expf(2.0f * a);
    float t = 1.0f - 2.0f / (e + 1.0f);   // large a -> e=inf -> t=1
    return v < 0.0f ? -t : t;
}

// split fp32 -> (hi = truncated bf16, lo = RNE bf16 of exact residual)
__device__ __forceinline__ void split1(float f, short& h, short& l) {
    unsigned u = __float_as_uint(f);
    h = (short)(u >> 16);
    float hf = __uint_as_float(u & 0xFFFF0000u);
    l = (short)bf16_rne(f - hf);
}

// one fused kernel: 256 l-rows x 16 d per block; 4 waves x 64 rows each
__global__ __launch_bounds__(256, 2) void sidechain_fused(
        const float* __restrict__ x, const float* __restrict__ W,
        float* __restrict__ out) {
    __shared__ unsigned short BsHi[7 * 16 * C_];   // [k][d_local][cin], XOR-swizzled granules
    __shared__ unsigned short BsLo[7 * 16 * C_];

    const int tid = threadIdx.x;
    const int b  = blockIdx.x >> 4;
    const int l0 = (blockIdx.x & 15) * 256;
    const int d0 = blockIdx.y * 16;

    const float* xb = x + (size_t)b * (L_ * C_);

    // ---- stage + convert W tile straight from fp32 global
    {
        const int dl = tid >> 4;       // 0..15: d row
        const int g  = tid & 15;       // cin granule (8 cins)
        const int gp = g ^ dl;         // swizzled granule slot
        const float* wp = W + (size_t)(d0 + dl) * CK + g * 56;  // 8 cins x 7 k, contiguous
        float wbuf[56];
#pragma unroll
        for (int i = 0; i < 14; ++i)
            *reinterpret_cast<float4*>(&wbuf[i * 4]) =
                *reinterpret_cast<const float4*>(&wp[i * 4]);
#pragma unroll
        for (int k = 0; k < 7; ++k) {
            short8v h, l;
#pragma unroll
            for (int c = 0; c < 8; ++c) {
                short hh, ll;
                split1(wbuf[c * 7 + k], hh, ll);
                h[c] = hh; l[c] = ll;
            }
            *reinterpret_cast<short8v*>(&BsHi[(k * 16 + dl) * C_ + gp * 8]) = h;
            *reinterpret_cast<short8v*>(&BsLo[(k * 16 + dl) * C_ + gp * 8]) = l;
        }
    }

    const int wv   = tid >> 6;
    const int lane = tid & 63;
    const int rA   = lane & 15;    // A row / B col(d) / D col
    const int kg   = lane >> 4;    // 0..3

    // ---- A fragments: load fp32, split in-register. 4 m-tiles x 4 K-steps
    short8v Ahi[4][4], Alo[4][4];
#pragma unroll
    for (int mt = 0; mt < 4; ++mt) {
        int r = l0 + 6 + wv * 64 + mt * 16 + rA;
        if (r > L_ - 1) r = L_ - 1;            // clamped rows feed masked-out outputs only
        const float* xr = xb + (size_t)r * C_;
#pragma unroll
        for (int ks = 0; ks < 4; ++ks) {
            const float* p = xr + ks * 32 + kg * 8;
            const float4 f0 = *reinterpret_cast<const float4*>(p);
            const float4 f1 = *reinterpret_cast<const float4*>(p + 4);
            const float f[8] = {f0.x, f0.y, f0.z, f0.w, f1.x, f1.y, f1.z, f1.w};
            short8v h, l;
#pragma unroll
            for (int c = 0; c < 8; ++c) {
                short hh, ll;
                split1(f[c], hh, ll);
                h[c] = hh; l[c] = ll;
            }
            Ahi[mt][ks] = h; Alo[mt][ks] = l;
        }
    }

    // ---- epilogue x values, hoisted: 10 rows cover r(0..3)+nt(0..6)
    const int dcol = d0 + rA;
    float xv[4][10];
#pragma unroll
    for (int mt = 0; mt < 4; ++mt) {
        int base = l0 + wv * 64 + mt * 16 + kg * 4;
#pragma unroll
        for (int r2 = 0; r2 < 10; ++r2) {
            int row = base + r2;
            if (row > L_ - 1) row = L_ - 1;    // OOB only for masked-out outputs
            xv[mt][r2] = xb[(size_t)row * C_ + dcol];
        }
    }
    __syncthreads();

    f32x4 oacc[4];
#pragma unroll
    for (int mt = 0; mt < 4; ++mt) oacc[mt] = (f32x4)(0.0f);

#pragma unroll
    for (int nt = 0; nt < 7; ++nt) {           // n-tile == tap k
        f32x4 acc[4];
#pragma unroll
        for (int mt = 0; mt < 4; ++mt) acc[mt] = (f32x4)(0.0f);
#pragma unroll
        for (int ks = 0; ks < 4; ++ks) {
            int gp = (ks * 4 + kg) ^ rA;
            const short8v Bh = *reinterpret_cast<const short8v*>(&BsHi[(nt * 16 + rA) * C_ + gp * 8]);
            const short8v Bl = *reinterpret_cast<const short8v*>(&BsLo[(nt * 16 + rA) * C_ + gp * 8]);
#pragma unroll
            for (int mt = 0; mt < 4; ++mt) {
                acc[mt] = __builtin_amdgcn_mfma_f32_16x16x32_bf16(Ahi[mt][ks], Bh, acc[mt], 0, 0, 0);
                acc[mt] = __builtin_amdgcn_mfma_f32_16x16x32_bf16(Ahi[mt][ks], Bl, acc[mt], 0, 0, 0);
                acc[mt] = __builtin_amdgcn_mfma_f32_16x16x32_bf16(Alo[mt][ks], Bh, acc[mt], 0, 0, 0);
            }
        }
        // fused FIR epilogue for tap nt (register-resident x)
#pragma unroll
        for (int mt = 0; mt < 4; ++mt)
#pragma unroll
            for (int r = 0; r < 4; ++r)
                oacc[mt][r] = fmaf(xv[mt][r + nt], fast_tanh(acc[mt][r]), oacc[mt][r]);
    }

#pragma unroll
    for (int mt = 0; mt < 4; ++mt) {
#pragma unroll
        for (int r = 0; r < 4; ++r) {
            int l = l0 + wv * 64 + mt * 16 + kg * 4 + r;
            if (l < LP) out[((size_t)b * LP + l) * C_ + dcol] = oacc[mt][r];
        }
    }
}

} // namespace

extern "C" void kernel_launch(void* const* d_in, const int* in_sizes, int n_in,
                              void* d_out, int out_size, void* d_ws, size_t ws_size,
                              hipStream_t stream) {
    const float* x = (const float*)d_in[0];
    const float* w = (const float*)d_in[1];
    float* out     = (float*)d_out;
    (void)d_ws; (void)ws_size; (void)in_sizes; (void)n_in; (void)out_size;

    dim3 grid(B_ * 16, C_ / 16);
    sidechain_fused<<<grid, dim3(256), 0, stream>>>(x, w, out);
}